// Round 3
// baseline (650.233 us; speedup 1.0000x reference)
//
#include <hip/hip_runtime.h>
#include <hip/hip_bf16.h>

// MambaMinimalBlock: B=4, L=2048, D_MODEL=1024, D_STATE=16, D_CONV=4,
// D_INNER=2048, BL=8192. fp32 in/out.
//
// R14: GEMM latency attack (R13 counters: MfmaUtil 21%, FETCH 139MB vs
// 40MB ideal, 1.56TB/s << 6.3 -> HBM-latency bound, ~900cy exposed/step):
// (a) NBUF=3 + counted s_waitcnt vmcnt(4) + raw s_barrier (T3/T4, m201
//     template combo). Stage tile t+2 after iter-t barrier; one barrier
//     per K-step; vmcnt never drained to 0 in the main loop.
// (b) T1 XCD-chunked block swizzle, column-major within each XCD chunk:
//     each XCD pins its 0.5-1MB weight col-panels in XCD-L2; 8 XCDs
//     sweep A row-panels in loose lockstep (L3 catches re-reads).
// Scan unchanged from R13 (NCHK 32, LDS B/C panel, hoisted fold).
//
// GEMMs: bf16 MFMA fp32 acc, inverse-swizzled gload source + swizzled
// ds_read (zero bank conflicts, R12/R13-verified image). bc: split-K
// hi/lo MFMA. absmax 1.95e-3 vs 5.59e-3 threshold (math unchanged).

typedef float  f32x4  __attribute__((ext_vector_type(4)));
typedef short  bf16x8 __attribute__((ext_vector_type(8)));

#define NCHK 32
#define CLEN 64
#define SW   8      // scan window (double-buffered)

__device__ __forceinline__ ushort f2bf(float f) {
    uint u = __float_as_uint(f);
    u += 0x7FFF + ((u >> 16) & 1);          // RNE
    return (ushort)(u >> 16);
}
__device__ __forceinline__ float bf2f(ushort h) {
    return __uint_as_float((uint)h << 16);
}
__device__ __forceinline__ float softplus_f(float x) {
    return fmaxf(x, 0.f) + __logf(1.f + __expf(-fabsf(x)));
}
__device__ __forceinline__ float silu_f(float x) {
    return x / (1.f + __expf(-x));
}

// swizzled LDS chunk address (ushort units): row stride 32, chunk q
// permuted by row: slot c = (q + (row>>1)) & 3.
__device__ __forceinline__ int lds_addr(int row, int q) {
    return (row << 5) + ((((q + (row >> 1)) & 3)) << 3);
}
__device__ __forceinline__ int lds_frag_off(int lane) {
    const int r = lane & 15, q = lane >> 4;
    return (r << 5) + ((((q + (r >> 1)) & 3)) << 3);
}

// async global->LDS, 16B per lane; LDS dest = wave-uniform base + lane*16.
__device__ __forceinline__ void gload16(const ushort* g, ushort* l) {
    __builtin_amdgcn_global_load_lds(
        (const __attribute__((address_space(1))) void*)g,
        (__attribute__((address_space(3))) void*)l,
        16, 0, 0);
}

__global__ __launch_bounds__(256)
void split_w_kernel(const float* __restrict__ src, ushort* __restrict__ hi,
                    ushort* __restrict__ lo)
{
    const int i = blockIdx.x * 256 + threadIdx.x;
    float4 v = ((const float4*)src)[i];
    ushort4 h, l;
    h.x = f2bf(v.x); l.x = f2bf(v.x - bf2f(h.x));
    h.y = f2bf(v.y); l.y = f2bf(v.y - bf2f(h.y));
    h.z = f2bf(v.z); l.z = f2bf(v.z - bf2f(h.z));
    h.w = f2bf(v.w); l.w = f2bf(v.w - bf2f(h.w));
    ((ushort4*)hi)[i] = h;
    ((ushort4*)lo)[i] = l;
}

__global__ __launch_bounds__(256)
void cvt_bf16_kernel(const float* __restrict__ src, ushort* __restrict__ dst)
{
    const int i = blockIdx.x * 256 + threadIdx.x;
    float4 v = ((const float4*)src)[i];
    ushort4 h;
    h.x = f2bf(v.x); h.y = f2bf(v.y); h.z = f2bf(v.z); h.w = f2bf(v.w);
    ((ushort4*)dst)[i] = h;
}

// C[M,N] = A[M,K](bf16) * B[N,K]^T(bf16), fp32 accumulate.
// 128x128 block, 4 waves x (4x4 of 16x16x32 MFMA). NBUF=3
// global_load_lds pipeline, counted vmcnt(4), raw barriers (1/K-step).
// 1D grid, XCD-chunked swizzle, col-major within chunk (NY=64 rows).
// NT = K/32 (template). EPI: 0 fp32, 1 softplus+bias fp32, 2 bf16.
template <int EPI, int NT>
__global__ __launch_bounds__(256)
void gemm_mfma(const ushort* __restrict__ A, const ushort* __restrict__ Bm,
               const float* __restrict__ bias, void* __restrict__ Cout,
               int N)
{
    __shared__ __attribute__((aligned(16))) ushort As[3][4096];  // 24 KB
    __shared__ __attribute__((aligned(16))) ushort Bs[3][4096];  // 24 KB

    const int K = NT * 32;
    const int tid  = threadIdx.x;
    const int lane = tid & 63;
    const int wave = tid >> 6;
    const int wm   = (wave >> 1) * 64;
    const int wn   = (wave & 1) * 64;

    // XCD-chunked swizzle (nwg % 8 == 0): XCD k owns q consecutive lin;
    // lin sweeps rows (by) fastest -> weight col-panel stays in XCD L2.
    const int nwg = gridDim.x;
    const int q8  = nwg >> 3;
    const int lin = (blockIdx.x & 7) * q8 + (blockIdx.x >> 3);
    const int row0 = (lin & 63) * 128;
    const int col0 = (lin >> 6) * 128;

    // staging: lane t writes LDS bytes wave*1024 + lane*16 within each
    // half-tile (rows tid/4, slot tid&3). Slot c holds global chunk
    // qsrc = (c - (row>>1)) & 3 so the LDS image matches lds_addr().
    const int crow = tid >> 2;            // 0..63 (row within half-tile)
    const int cq   = tid & 3;             // LDS slot
    const int qsrc = (cq - (crow >> 1)) & 3;   // global 16B chunk to fetch
    const ushort* Ag0 = A  + (size_t)(row0 + crow) * K + qsrc * 8;
    const ushort* Ag1 = A  + (size_t)(row0 + crow + 64) * K + qsrc * 8;
    const ushort* Bg0 = Bm + (size_t)(col0 + crow) * K + qsrc * 8;
    const ushort* Bg1 = Bm + (size_t)(col0 + crow + 64) * K + qsrc * 8;

    const int wbase = wave * 512;   // ushort units

    const int flo = lds_frag_off(lane);
    const int fra = (wm << 5) + flo;
    const int frb = (wn << 5) + flo;

    f32x4 acc[4][4];
#pragma unroll
    for (int mi = 0; mi < 4; ++mi)
#pragma unroll
        for (int ni = 0; ni < 4; ++ni)
            acc[mi][ni] = (f32x4){0.f, 0.f, 0.f, 0.f};

#define STAGE(bi, kof)                                        \
    do {                                                      \
        gload16(Ag0 + (kof), As[bi] + wbase);                 \
        gload16(Ag1 + (kof), As[bi] + 2048 + wbase);          \
        gload16(Bg0 + (kof), Bs[bi] + wbase);                 \
        gload16(Bg1 + (kof), Bs[bi] + 2048 + wbase);          \
    } while (0)

    auto body = [&](const ushort* Ac, const ushort* Bc) {
        bf16x8 af[4], bf[4];
#pragma unroll
        for (int mi = 0; mi < 4; ++mi)
            af[mi] = *(const bf16x8*)(Ac + fra + mi * 512);
#pragma unroll
        for (int ni = 0; ni < 4; ++ni)
            bf[ni] = *(const bf16x8*)(Bc + frb + ni * 512);
#pragma unroll
        for (int mi = 0; mi < 4; ++mi)
#pragma unroll
            for (int ni = 0; ni < 4; ++ni)
                acc[mi][ni] = __builtin_amdgcn_mfma_f32_16x16x32_bf16(
                    af[mi], bf[ni], acc[mi][ni], 0, 0, 0);
    };

    // prologue: stage tiles 0 and 1.
    STAGE(0, 0);
    STAGE(1, 32);

    int bcur = 0;
    for (int t = 0; t < NT - 1; ++t) {
        // own tile-t loads done (<=4 newer = tile t+1's may remain).
        asm volatile("s_waitcnt vmcnt(4)" ::: "memory");
        __builtin_amdgcn_s_barrier();        // tile t staged by ALL waves;
        __builtin_amdgcn_sched_barrier(0);   // all waves done reading t-1
        if (t + 2 < NT) {
            int b2 = bcur + 2; if (b2 >= 3) b2 -= 3;   // == (t-1)%3 slot
            STAGE(b2, (t + 2) * 32);
        }
        body(As[bcur], Bs[bcur]);
        ++bcur; if (bcur == 3) bcur = 0;
    }
    asm volatile("s_waitcnt vmcnt(0)" ::: "memory");
    __builtin_amdgcn_s_barrier();
    __builtin_amdgcn_sched_barrier(0);
    body(As[bcur], Bs[bcur]);
#undef STAGE

#pragma unroll
    for (int mi = 0; mi < 4; ++mi) {
        const int rg = row0 + wm + mi * 16 + (lane >> 4) * 4;
#pragma unroll
        for (int ni = 0; ni < 4; ++ni) {
            const int cg = col0 + wn + ni * 16 + (lane & 15);
            f32x4 v = acc[mi][ni];
            if (EPI == 1) {
                const float bv = bias[cg];
#pragma unroll
                for (int r = 0; r < 4; ++r) v[r] = softplus_f(v[r] + bv);
            }
#pragma unroll
            for (int r = 0; r < 4; ++r) {
                if (EPI == 2)
                    ((ushort*)Cout)[(size_t)(rg + r) * N + cg] = f2bf(v[r]);
                else
                    ((float*)Cout)[(size_t)(rg + r) * N + cg] = v[r];
            }
        }
    }
}

// Split-K bc GEMM: part[ks] = xc[:, ks*256:(ks+1)*256] @ Wx^T slice.
__global__ __launch_bounds__(256)
void gemm_bc_mfma(const ushort* __restrict__ A, const ushort* __restrict__ Bh,
                  const ushort* __restrict__ Bl, float* __restrict__ part)
{
    __shared__ __attribute__((aligned(16))) ushort As[4096];
    __shared__ __attribute__((aligned(16))) ushort Bhs[1024];
    __shared__ __attribute__((aligned(16))) ushort Bls[1024];

    const int tid  = threadIdx.x;
    const int lane = tid & 63;
    const int wave = tid >> 6;
    const int ks   = blockIdx.x;     // 0..7
    const int mb   = blockIdx.y;     // 0..63
    const int row0 = mb * 128;
    const int kb   = ks * 256;

    const int crow = tid >> 2;
    const int cq   = tid & 3;
    const ushort* Ag0 = A + (size_t)(row0 + crow) * 2048 + kb + cq * 8;
    const ushort* Ag1 = A + (size_t)(row0 + crow + 64) * 2048 + kb + cq * 8;
    const int st0 = lds_addr(crow, cq);
    const int st1 = st0 + 2048;

    const int t2   = tid & 127;
    const int brow = t2 >> 2;        // 0..31
    const int bq   = t2 & 3;
    const ushort* Bg = (tid < 128 ? Bh : Bl) + (size_t)brow * 2048 + kb + bq * 8;
    ushort* Bdst     = (tid < 128 ? Bhs : Bls) + lds_addr(brow, bq);

    const int wm  = wave * 32;
    const int flo = lds_frag_off(lane);
    const int fra = (wm << 5) + flo;
    const int frb = flo;

    f32x4 acc[2][2];
#pragma unroll
    for (int mi = 0; mi < 2; ++mi)
#pragma unroll
        for (int ni = 0; ni < 2; ++ni)
            acc[mi][ni] = (f32x4){0.f, 0.f, 0.f, 0.f};

    uint4 ra0 = *(const uint4*)Ag0, ra1 = *(const uint4*)Ag1;
    uint4 rb  = *(const uint4*)Bg;

    for (int kt = 0; kt < 8; ++kt) {
        __syncthreads();
        *(uint4*)(As + st0) = ra0;
        *(uint4*)(As + st1) = ra1;
        *(uint4*)Bdst = rb;
        __syncthreads();
        if (kt < 7) {
            ra0 = *(const uint4*)(Ag0 + (kt + 1) * 32);
            ra1 = *(const uint4*)(Ag1 + (kt + 1) * 32);
            rb  = *(const uint4*)(Bg + (kt + 1) * 32);
        }
        bf16x8 af[2], bhf[2], blf[2];
#pragma unroll
        for (int mi = 0; mi < 2; ++mi)
            af[mi] = *(const bf16x8*)(As + fra + mi * 512);
#pragma unroll
        for (int ni = 0; ni < 2; ++ni) {
            bhf[ni] = *(const bf16x8*)(Bhs + frb + ni * 512);
            blf[ni] = *(const bf16x8*)(Bls + frb + ni * 512);
        }
#pragma unroll
        for (int mi = 0; mi < 2; ++mi)
#pragma unroll
            for (int ni = 0; ni < 2; ++ni) {
                acc[mi][ni] = __builtin_amdgcn_mfma_f32_16x16x32_bf16(
                    af[mi], bhf[ni], acc[mi][ni], 0, 0, 0);
                acc[mi][ni] = __builtin_amdgcn_mfma_f32_16x16x32_bf16(
                    af[mi], blf[ni], acc[mi][ni], 0, 0, 0);
            }
    }

#pragma unroll
    for (int mi = 0; mi < 2; ++mi) {
        const int rg = row0 + wm + mi * 16 + (lane >> 4) * 4;
#pragma unroll
        for (int ni = 0; ni < 2; ++ni) {
            const int cg = ni * 16 + (lane & 15);
            f32x4 v = acc[mi][ni];
#pragma unroll
            for (int r = 0; r < 4; ++r)
                part[((size_t)ks * 8192 + rg + r) * 32 + cg] = v[r];
        }
    }
}

__global__ __launch_bounds__(256)
void bc_reduce_kernel(const float* __restrict__ part, float* __restrict__ bc)
{
    const int i = blockIdx.x * 256 + threadIdx.x;   // 262144
    float s = 0.f;
#pragma unroll
    for (int ks = 0; ks < 8; ++ks)
        s += part[(size_t)ks * 262144 + i];
    bc[i] = s;
}

// Depthwise causal conv1d (4 taps) + bias + silu; bf16 in, bf16 out.
__global__ __launch_bounds__(256)
void conv_silu_kernel(const ushort* __restrict__ xi, const float* __restrict__ cw,
                      const float* __restrict__ cb, ushort* __restrict__ xc)
{
    const int idx = blockIdx.x * 256 + threadIdx.x;
    const int e   = (idx & 511) << 2;
    const int row = idx >> 9;
    const int l   = row & 2047;

    const float4 w0 = *(const float4*)(cw + (size_t)(e + 0) * 4);
    const float4 w1 = *(const float4*)(cw + (size_t)(e + 1) * 4);
    const float4 w2 = *(const float4*)(cw + (size_t)(e + 2) * 4);
    const float4 w3 = *(const float4*)(cw + (size_t)(e + 3) * 4);

    float4 acc = *(const float4*)(cb + e);

#define CONV_TAP(K_, WSEL)                                                  \
    {                                                                       \
        ushort4 t = *(const ushort4*)(xi + (size_t)(row - (K_)) * 2048 + e);\
        acc.x = fmaf(bf2f(t.x), w0.WSEL, acc.x);                            \
        acc.y = fmaf(bf2f(t.y), w1.WSEL, acc.y);                            \
        acc.z = fmaf(bf2f(t.z), w2.WSEL, acc.z);                            \
        acc.w = fmaf(bf2f(t.w), w3.WSEL, acc.w);                            \
    }
    if (l >= 3) CONV_TAP(3, x)
    if (l >= 2) CONV_TAP(2, y)
    if (l >= 1) CONV_TAP(1, z)
    CONV_TAP(0, w)
#undef CONV_TAP

    ushort4 o;
    o.x = f2bf(silu_f(acc.x)); o.y = f2bf(silu_f(acc.y));
    o.z = f2bf(silu_f(acc.z)); o.w = f2bf(silu_f(acc.w));
    *(ushort4*)(xc + (size_t)row * 2048 + e) = o;
}

// ---- d-parallel chunked selective scan (NCHK chunks of CLEN) ----

// Pass 1: chunks 0..NCHK-2, h from 0, writes he + P = exp(A * sum dt).
// B panel for the chunk staged in LDS (broadcast reads, no L2 dep chain).
__global__ __launch_bounds__(256)
void scan_part1(const ushort* __restrict__ xcb, const float* __restrict__ dbuf,
                const float* __restrict__ bcbuf, const float* __restrict__ A_log,
                float* __restrict__ sum_h, float* __restrict__ sum_p)
{
    __shared__ float bcs[CLEN * 32];           // 8 KB

    const int c    = blockIdx.x >> 5;          // 0..NCHK-2
    const int b    = (blockIdx.x >> 3) & 3;
    const int dblk = blockIdx.x & 7;
    const int d    = dblk * 256 + threadIdx.x;

    const size_t row0 = (size_t)b * 2048 + (size_t)c * CLEN;
    const float* bcp  = bcbuf + row0 * 32;

    // cooperative stage of the chunk's B/C panel (CLEN*32 floats)
#pragma unroll
    for (int i = 0; i < (CLEN * 32) / (4 * 256); ++i)
        ((float4*)bcs)[threadIdx.x + i * 256] =
            ((const float4*)bcp)[threadIdx.x + i * 256];

    float Aval[16];
#pragma unroll
    for (int q = 0; q < 4; ++q) {
        float4 al = *(const float4*)(A_log + (size_t)d * 16 + q * 4);
        Aval[q*4+0] = -__expf(al.x); Aval[q*4+1] = -__expf(al.y);
        Aval[q*4+2] = -__expf(al.z); Aval[q*4+3] = -__expf(al.w);
    }

    const float*  dp = dbuf + row0 * 2048 + d;
    const ushort* xp = xcb  + row0 * 2048 + d;

    float h[16];
#pragma unroll
    for (int s = 0; s < 16; ++s) h[s] = 0.f;
    float S = 0.f;

    float wdt[SW], wxv[SW];
#pragma unroll
    for (int j = 0; j < SW; ++j) {
        wdt[j] = dp[(size_t)j * 2048];
        wxv[j] = bf2f(xp[(size_t)j * 2048]);
    }
    __syncthreads();

    for (int l0 = 0; l0 < CLEN; l0 += SW) {
        float ndt[SW], nxv[SW];
        const bool more = (l0 + SW) < CLEN;
        if (more) {
#pragma unroll
            for (int j = 0; j < SW; ++j) {
                const size_t o = (size_t)(l0 + SW + j);
                ndt[j] = dp[o * 2048];
                nxv[j] = bf2f(xp[o * 2048]);
            }
        }
#pragma unroll
        for (int j = 0; j < SW; ++j) {
            const int l = l0 + j;
            const float dt = wdt[j];
            const float t  = dt * wxv[j];
            S += dt;
#pragma unroll
            for (int s = 0; s < 16; ++s)
                h[s] = __expf(dt * Aval[s]) * h[s] + bcs[l * 32 + s] * t;
        }
        if (more) {
#pragma unroll
            for (int j = 0; j < SW; ++j) { wdt[j] = ndt[j]; wxv[j] = nxv[j]; }
        }
    }

    float* sh = sum_h + ((((size_t)c * 4 + b) * 2048 + d) << 4);
    float* sp = sum_p + ((((size_t)c * 4 + b) * 2048 + d) << 4);
#pragma unroll
    for (int q = 0; q < 4; ++q) {
        *(float4*)(sh + q * 4) = make_float4(h[q*4], h[q*4+1], h[q*4+2], h[q*4+3]);
        *(float4*)(sp + q * 4) = make_float4(__expf(Aval[q*4] * S), __expf(Aval[q*4+1] * S),
                                             __expf(Aval[q*4+2] * S), __expf(Aval[q*4+3] * S));
    }
}

// Sequential prefix over chunk summaries, in-place into sum_h.
// After: sum_h slot c holds the scan state at the START of chunk c+1.
// Grid: 32 blocks (4 b x 8 dblk) x 256 threads; NCHK-1 dependent steps.
__global__ __launch_bounds__(256)
void scan_fold(float* __restrict__ sum_h, const float* __restrict__ sum_p)
{
    const int b = blockIdx.x >> 3;
    const int d = (blockIdx.x & 7) * 256 + threadIdx.x;

    float h[16];
#pragma unroll
    for (int s = 0; s < 16; ++s) h[s] = 0.f;

    for (int c = 0; c < NCHK - 1; ++c) {
        float*       sh = sum_h + ((((size_t)c * 4 + b) * 2048 + d) << 4);
        const float* sp = sum_p + ((((size_t)c * 4 + b) * 2048 + d) << 4);
#pragma unroll
        for (int q = 0; q < 4; ++q) {
            float4 vh = *(const float4*)(sh + q * 4);
            float4 vp = *(const float4*)(sp + q * 4);
            h[q*4+0] = vh.x + vp.x * h[q*4+0];
            h[q*4+1] = vh.y + vp.y * h[q*4+1];
            h[q*4+2] = vh.z + vp.z * h[q*4+2];
            h[q*4+3] = vh.w + vp.w * h[q*4+3];
        }
#pragma unroll
        for (int q = 0; q < 4; ++q)
            *(float4*)(sh + q * 4) = make_float4(h[q*4], h[q*4+1], h[q*4+2], h[q*4+3]);
    }
}

// Pass 2: all NCHK chunks; load start state (sum_h[c-1]), scan, y bf16 out.
// B/C panel for the chunk staged in LDS.
__global__ __launch_bounds__(256)
void scan_part2(const ushort* __restrict__ zbuf, const ushort* __restrict__ xcb,
                const float* __restrict__ dbuf, const float* __restrict__ bcbuf,
                const float* __restrict__ A_log, const float* __restrict__ Dp,
                const float* __restrict__ sum_h, ushort* __restrict__ ybuf)
{
    __shared__ float bcs[CLEN * 32];           // 8 KB

    const int c    = blockIdx.x >> 5;          // 0..NCHK-1
    const int b    = (blockIdx.x >> 3) & 3;
    const int dblk = blockIdx.x & 7;
    const int d    = dblk * 256 + threadIdx.x;

    const size_t row0 = (size_t)b * 2048 + (size_t)c * CLEN;
    const float* bcp  = bcbuf + row0 * 32;

#pragma unroll
    for (int i = 0; i < (CLEN * 32) / (4 * 256); ++i)
        ((float4*)bcs)[threadIdx.x + i * 256] =
            ((const float4*)bcp)[threadIdx.x + i * 256];

    float Aval[16];
#pragma unroll
    for (int q = 0; q < 4; ++q) {
        float4 al = *(const float4*)(A_log + (size_t)d * 16 + q * 4);
        Aval[q*4+0] = -__expf(al.x); Aval[q*4+1] = -__expf(al.y);
        Aval[q*4+2] = -__expf(al.z); Aval[q*4+3] = -__expf(al.w);
    }
    const float Dv = Dp[d];

    float h[16];
    if (c == 0) {
#pragma unroll
        for (int s = 0; s < 16; ++s) h[s] = 0.f;
    } else {
        const float* sh = sum_h + ((((size_t)(c - 1) * 4 + b) * 2048 + d) << 4);
#pragma unroll
        for (int q = 0; q < 4; ++q)
            *(float4*)&h[q*4] = *(const float4*)(sh + q * 4);
    }

    const float*  dp = dbuf + row0 * 2048 + d;
    const ushort* xp = xcb  + row0 * 2048 + d;
    const ushort* zp = zbuf + row0 * 2048 + d;
    ushort*       yp = ybuf + row0 * 2048 + d;

    float wdt[SW], wxv[SW], wzv[SW];
#pragma unroll
    for (int j = 0; j < SW; ++j) {
        wdt[j] = dp[(size_t)j * 2048];
        wxv[j] = bf2f(xp[(size_t)j * 2048]);
        wzv[j] = bf2f(zp[(size_t)j * 2048]);
    }
    __syncthreads();

    for (int l0 = 0; l0 < CLEN; l0 += SW) {
        float ndt[SW], nxv[SW], nzv[SW];
        const bool more = (l0 + SW) < CLEN;
        if (more) {
#pragma unroll
            for (int j = 0; j < SW; ++j) {
                const size_t o = (size_t)(l0 + SW + j);
                ndt[j] = dp[o * 2048];
                nxv[j] = bf2f(xp[o * 2048]);
                nzv[j] = bf2f(zp[o * 2048]);
            }
        }
#pragma unroll
        for (int j = 0; j < SW; ++j) {
            const int l = l0 + j;
            const float dt = wdt[j];
            const float t  = dt * wxv[j];
#pragma unroll
            for (int s = 0; s < 16; ++s)
                h[s] = __expf(dt * Aval[s]) * h[s] + bcs[l * 32 + s] * t;
            float y0 = 0.f, y1 = 0.f, y2 = 0.f, y3 = 0.f;
#pragma unroll
            for (int s = 0; s < 16; s += 4) {
                y0 = fmaf(h[s+0], bcs[l * 32 + 16 + s + 0], y0);
                y1 = fmaf(h[s+1], bcs[l * 32 + 16 + s + 1], y1);
                y2 = fmaf(h[s+2], bcs[l * 32 + 16 + s + 2], y2);
                y3 = fmaf(h[s+3], bcs[l * 32 + 16 + s + 3], y3);
            }
            float y = (y0 + y1) + (y2 + y3) + Dv * wxv[j];
            yp[(size_t)l * 2048] = f2bf(y * silu_f(wzv[j]));
        }
        if (more) {
#pragma unroll
            for (int j = 0; j < SW; ++j) {
                wdt[j] = ndt[j]; wxv[j] = nxv[j]; wzv[j] = nzv[j];
            }
        }
    }
}

extern "C" void kernel_launch(void* const* d_in, const int* in_sizes, int n_in,
                              void* d_out, int out_size, void* d_ws, size_t ws_size,
                              hipStream_t stream)
{
    const float* x          = (const float*)d_in[0];
    const float* in_proj_w  = (const float*)d_in[1];
    const float* conv_w     = (const float*)d_in[2];
    const float* conv_b     = (const float*)d_in[3];
    const float* x_proj_w   = (const float*)d_in[4];
    const float* dt_proj_w  = (const float*)d_in[5];
    const float* dt_proj_b  = (const float*)d_in[6];
    const float* A_log      = (const float*)d_in[7];
    const float* Dp         = (const float*)d_in[8];
    const float* out_proj_w = (const float*)d_in[9];
    float* out = (float*)d_out;

    // Workspace (~232 MB of 256 MiB)
    ushort* XI    = (ushort*)d_ws;                    // 32 MB; later Y'
    ushort* Z     = XI + 16777216;                    // 32 MB
    ushort* XC2   = Z + 16777216;                     // 32 MB
    float*  DELTA = (float*)(XC2 + 16777216);         // 64 MB
    ushort* XP    = (ushort*)DELTA;                   // x' bf16 (pre-DELTA)
    ushort* WINH  = (ushort*)(DELTA + 16777216);      // 8 MB [4096,1024] bf16
    ushort* WDTH  = WINH + 4194304;                   // 8 MB [2048,2048] bf16
    ushort* WOUTH = WDTH + 4194304;                   // 4 MB [1024,2048] bf16
    float*  BC    = (float*)(WOUTH + 2097152);        // 1 MB
    float*  SUMH  = BC + 262144;                      // 16.8 MB (32*4*2048*16)
    float*  SUMP  = SUMH + 4194304;                   // 16.8 MB
    ushort* XPH   = (ushort*)(SUMP + 4194304);        // 128 KB (x_proj hi)
    ushort* XPL   = XPH + 65536;                      // 128 KB
    float*  PART  = (float*)(XPL + 65536);            // 8 MB split-K partials
    ushort* Yp    = XI;

    const dim3 blk(256);

    // 0) conversions (weights plain bf16 except x_proj hi/lo)
    cvt_bf16_kernel<<<dim3(8192), blk, 0, stream>>>(x, XP);
    cvt_bf16_kernel<<<dim3(4096), blk, 0, stream>>>(in_proj_w, WINH);
    cvt_bf16_kernel<<<dim3(4096), blk, 0, stream>>>(dt_proj_w, WDTH);
    cvt_bf16_kernel<<<dim3(2048), blk, 0, stream>>>(out_proj_w, WOUTH);
    split_w_kernel<<<dim3(64),    blk, 0, stream>>>(x_proj_w, XPH, XPL);

    // 1) xi, z  (K=1024 -> NT=32; grid 16 cols x 64 rows = 1024)
    gemm_mfma<2, 32><<<dim3(1024), blk, 0, stream>>>(XP, WINH, nullptr, XI, 2048);
    gemm_mfma<2, 32><<<dim3(1024), blk, 0, stream>>>(XP, WINH + 2097152, nullptr, Z, 2048);

    // 2) xc = silu(conv(xi) + b)
    conv_silu_kernel<<<dim3(16384), blk, 0, stream>>>(XI, conv_w, conv_b, XC2);

    // 3) delta = softplus(xc @ Wdt^T + b)  (K=2048 -> NT=64)
    gemm_mfma<1, 64><<<dim3(1024), blk, 0, stream>>>(XC2, WDTH, dt_proj_b, DELTA, 2048);

    // 4) bc = xc @ x_proj_w^T  (split-K MFMA + reduce)
    gemm_bc_mfma<<<dim3(8, 64), blk, 0, stream>>>(XC2, XPH, XPL, PART);
    bc_reduce_kernel<<<dim3(1024), blk, 0, stream>>>(PART, BC);

    // 5) chunked scan: pass1 -> prefix fold -> pass2
    scan_part1<<<dim3((NCHK - 1) * 32), blk, 0, stream>>>(XC2, DELTA, BC, A_log, SUMH, SUMP);
    scan_fold<<<dim3(32), blk, 0, stream>>>(SUMH, SUMP);
    scan_part2<<<dim3(NCHK * 32), blk, 0, stream>>>(Z, XC2, DELTA, BC, A_log, Dp,
                                                    SUMH, Yp);

    // 6) out = y @ Wout^T  (K=2048 -> NT=64; grid 8 x 64 = 512)
    gemm_mfma<0, 64><<<dim3(512), blk, 0, stream>>>(Yp, WOUTH, nullptr, out, 1024);
}

// Round 4
// 556.737 us; speedup vs baseline: 1.1679x; 1.1679x over previous
//
#include <hip/hip_runtime.h>
#include <hip/hip_bf16.h>

// MambaMinimalBlock: B=4, L=2048, D_MODEL=1024, D_STATE=16, D_CONV=4,
// D_INNER=2048, BL=8192. fp32 in/out.
//
// R15: big GEMMs moved to the 256^2 8-phase counted-vmcnt template (m201:
// 1563TF/62% MfmaUtil; our 128^2 2-phase structures were pinned at 21%
// MfmaUtil = the known ~600TF 2-phase ceiling, m233/m230). 8 waves
// (2M x 4N), BK=64, LDS 2 x (A32K+B32K) = 128KB, per-phase
// {ds-read || 2x global_load_lds || barrier; lgkmcnt0; setprio; 16 MFMA;
// barrier}, vmcnt(4) at phases 4/8 only (derived: 12 outstanding,
// retire 8, leave 4). XOR swizzle chunk^=(row&7) w/ inverse-swizzled
// per-lane global source (rule #21). Staging ledger (overwrite-safety):
//   half-tile last-READ phase -> STAGED phase (>= +1 barrier later):
//   A(u) read ph0,ph2 -> A(u+2) staged ph4,ph5 (same buf)
//   B(u) read ph0,ph1 -> B(u+2) staged ph2,ph3
//   A(u+1) staged ph0,ph1 (buf^1, last read prev ph4,ph6)
//   B(u+3) staged ph6,ph7 (buf^1, last read ph4,ph5)
// K accumulation order bit-identical to R13 (32-wide ascending) ->
// absmax unchanged (1.95e-3 vs 5.59e-3 threshold).
// xi+z fused into one N=4096 GEMM. Scan/conv/bc frozen at R13.

typedef float  f32x4  __attribute__((ext_vector_type(4)));
typedef short  bf16x8 __attribute__((ext_vector_type(8)));

#define NCHK 32
#define CLEN 64
#define SW   8      // scan window (double-buffered)

__device__ __forceinline__ ushort f2bf(float f) {
    uint u = __float_as_uint(f);
    u += 0x7FFF + ((u >> 16) & 1);          // RNE
    return (ushort)(u >> 16);
}
__device__ __forceinline__ float bf2f(ushort h) {
    return __uint_as_float((uint)h << 16);
}
__device__ __forceinline__ float softplus_f(float x) {
    return fmaxf(x, 0.f) + __logf(1.f + __expf(-fabsf(x)));
}
__device__ __forceinline__ float silu_f(float x) {
    return x / (1.f + __expf(-x));
}

// ---- legacy 64-row swizzle (bc kernel) ----
__device__ __forceinline__ int lds_addr(int row, int q) {
    return (row << 5) + ((((q + (row >> 1)) & 3)) << 3);
}
__device__ __forceinline__ int lds_frag_off(int lane) {
    const int r = lane & 15, q = lane >> 4;
    return (r << 5) + ((((q + (r >> 1)) & 3)) << 3);
}

// async global->LDS, 16B/lane; LDS dest must be wave-uniform (HW adds
// lane*16); global src is per-lane.
__device__ __forceinline__ void gload16(const ushort* g, ushort* l) {
    __builtin_amdgcn_global_load_lds(
        (const __attribute__((address_space(1))) void*)g,
        (__attribute__((address_space(3))) void*)l,
        16, 0, 0);
}

__global__ __launch_bounds__(256)
void split_w_kernel(const float* __restrict__ src, ushort* __restrict__ hi,
                    ushort* __restrict__ lo)
{
    const int i = blockIdx.x * 256 + threadIdx.x;
    float4 v = ((const float4*)src)[i];
    ushort4 h, l;
    h.x = f2bf(v.x); l.x = f2bf(v.x - bf2f(h.x));
    h.y = f2bf(v.y); l.y = f2bf(v.y - bf2f(h.y));
    h.z = f2bf(v.z); l.z = f2bf(v.z - bf2f(h.z));
    h.w = f2bf(v.w); l.w = f2bf(v.w - bf2f(h.w));
    ((ushort4*)hi)[i] = h;
    ((ushort4*)lo)[i] = l;
}

__global__ __launch_bounds__(256)
void cvt_bf16_kernel(const float* __restrict__ src, ushort* __restrict__ dst)
{
    const int i = blockIdx.x * 256 + threadIdx.x;
    float4 v = ((const float4*)src)[i];
    ushort4 h;
    h.x = f2bf(v.x); h.y = f2bf(v.y); h.z = f2bf(v.z); h.w = f2bf(v.w);
    ((ushort4*)dst)[i] = h;
}

// ---- 256x256 8-phase GEMM: C[M,N] = A[M,K](bf16) x B[N,K]^T(bf16) ----
// 512 threads = 8 waves, wave (w>>2) in M (2x128), (w&3) in N (4x64).
// Per wave: 8x4 frags of 16x16, acc 128 VGPR. K-tile = 64 (2 k-slices).
// LDS image: per half [128 rows][8 chunks of 16B], stored chunk
// c = q ^ (row&7); staged linearly (HW) from inverse-swizzled source.
// EPI: 0 fp32 -> C0; 1 softplus(+bias) fp32 -> C0; 2 bf16 split
// (col<2048 -> C0 else C1, both stride Nst).
template <int EPI, int NTKT>
__global__ __launch_bounds__(512, 1)
void gemm256(const ushort* __restrict__ A, const ushort* __restrict__ Bm,
             const float* __restrict__ bias, void* __restrict__ C0,
             void* __restrict__ C1, int Nst)
{
    __shared__ __attribute__((aligned(16))) ushort As[2][16384];  // 64 KB
    __shared__ __attribute__((aligned(16))) ushort Bs[2][16384];  // 64 KB

    const int K   = NTKT * 64;
    const int tid = threadIdx.x;
    const int l   = tid & 63;
    const int w   = tid >> 6;

    const int row0 = (blockIdx.x & 31) * 256;
    const int col0 = (blockIdx.x >> 5) * 256;

    // staging per-thread: lane l covers row (l>>3) of an 8-row stripe,
    // global chunk q = (l&7) ^ (l>>3)  (inverse of LDS image swizzle).
    const int srow = l >> 3;
    const int sq   = (l & 7) ^ srow;
    const ushort* gA = A  + (size_t)(row0 + w * 16 + srow) * K + sq * 8;
    const ushort* gB = Bm + (size_t)(col0 + w * 16 + srow) * K + sq * 8;
    const int ldst = w * 1024;          // wave-uniform LDS base (ushorts)

    // fragment-read per-thread constants
    const int la  = l & 15, kc = l >> 4, xr = l & 7;
    const int ck0 = ((0 + kc) ^ xr) * 8;      // k-slice 0 chunk offset
    const int ck1 = ((4 + kc) ^ xr) * 8;      // k-slice 1
    const int aoff = (w >> 2) * 8192 + la * 64;
    const int boff = ((w & 3) >> 1) * 8192 + (((w & 3) & 1) * 64 + la) * 64;

    f32x4 acc[8][4];
#pragma unroll
    for (int m = 0; m < 8; ++m)
#pragma unroll
        for (int n = 0; n < 4; ++n)
            acc[m][n] = (f32x4){0.f, 0.f, 0.f, 0.f};

    bf16x8 af[4][2], bf[4][2];

#define STAGE(dstbase, gsrc, h, kt)                                         \
    do {                                                                    \
        gload16((gsrc) + (size_t)((h) * 128) * K + (size_t)(kt) * 64,       \
                (dstbase) + (h) * 8192 + ldst);                             \
        gload16((gsrc) + (size_t)((h) * 128 + 8) * K + (size_t)(kt) * 64,   \
                (dstbase) + (h) * 8192 + ldst + 512);                       \
    } while (0)

#define READ_AF(b, mbase)                                                   \
    _Pragma("unroll")                                                       \
    for (int m = 0; m < 4; ++m) {                                           \
        af[m][0] = *(const bf16x8*)(As[b] + aoff + (mbase + m) * 1024 + ck0); \
        af[m][1] = *(const bf16x8*)(As[b] + aoff + (mbase + m) * 1024 + ck1); \
    }

#define READ_BF(b, nbase)                                                   \
    _Pragma("unroll")                                                       \
    for (int n = 0; n < 2; ++n) {                                           \
        bf[(nbase) + n][0] = *(const bf16x8*)(Bs[b] + boff + ((nbase) + n) * 1024 + ck0); \
        bf[(nbase) + n][1] = *(const bf16x8*)(Bs[b] + boff + ((nbase) + n) * 1024 + ck1); \
    }

#define MFMA_Q(mbase, nbase)                                                \
    _Pragma("unroll")                                                       \
    for (int m = 0; m < 4; ++m)                                             \
    _Pragma("unroll")                                                       \
    for (int n = 0; n < 2; ++n) {                                           \
        acc[(mbase) + m][(nbase) + n] = __builtin_amdgcn_mfma_f32_16x16x32_bf16( \
            af[m][0], bf[(nbase) + n][0], acc[(mbase) + m][(nbase) + n], 0, 0, 0); \
        acc[(mbase) + m][(nbase) + n] = __builtin_amdgcn_mfma_f32_16x16x32_bf16( \
            af[m][1], bf[(nbase) + n][1], acc[(mbase) + m][(nbase) + n], 0, 0, 0); \
    }

#define SYNC_PRE()                                                          \
    do { __builtin_amdgcn_s_barrier();                                      \
         asm volatile("s_waitcnt lgkmcnt(0)" ::: "memory");                 \
         __builtin_amdgcn_sched_barrier(0);                                 \
         __builtin_amdgcn_s_setprio(1); } while (0)

#define SYNC_POST()                                                         \
    do { __builtin_amdgcn_s_setprio(0);                                     \
         __builtin_amdgcn_s_barrier();                                      \
         __builtin_amdgcn_sched_barrier(0); } while (0)

#define BOUNDARY()                                                          \
    do { asm volatile("s_waitcnt vmcnt(4)" ::: "memory");                   \
         __builtin_amdgcn_s_barrier();                                      \
         __builtin_amdgcn_sched_barrier(0); } while (0)

    // prologue: A(0), B(0), B(1); wait oldest 8 (= all of K-tile 0).
    STAGE(As[0], gA, 0, 0);
    STAGE(As[0], gA, 1, 0);
    STAGE(Bs[0], gB, 0, 0);
    STAGE(Bs[0], gB, 1, 0);
    STAGE(Bs[1], gB, 0, 1);
    STAGE(Bs[1], gB, 1, 1);
    BOUNDARY();

    const int NITER = NTKT / 2;
    for (int t = 0; t < NITER; ++t) {
        const int kt1 = 2 * t + 1;
        const int kt2 = (2 * t + 2 < NTKT) ? 2 * t + 2 : NTKT - 1;  // clamp
        const int kt3 = (2 * t + 3 < NTKT) ? 2 * t + 3 : NTKT - 1;  // (dead slots)

        // ---- K-tile 2t from buf0 ----
        READ_AF(0, 0); READ_BF(0, 0);
        STAGE(As[1], gA, 0, kt1);
        SYNC_PRE(); MFMA_Q(0, 0); SYNC_POST();      // ph0

        READ_BF(0, 2);
        STAGE(As[1], gA, 1, kt1);
        SYNC_PRE(); MFMA_Q(0, 2); SYNC_POST();      // ph1

        READ_AF(0, 4);
        STAGE(Bs[0], gB, 0, kt2);
        SYNC_PRE(); MFMA_Q(4, 0); SYNC_POST();      // ph2

        STAGE(Bs[0], gB, 1, kt2);
        SYNC_PRE(); MFMA_Q(4, 2); SYNC_POST();      // ph3

        BOUNDARY();                                  // K-tile 2t+1 ready

        // ---- K-tile 2t+1 from buf1 ----
        READ_AF(1, 0); READ_BF(1, 0);
        STAGE(As[0], gA, 0, kt2);
        SYNC_PRE(); MFMA_Q(0, 0); SYNC_POST();      // ph4

        READ_BF(1, 2);
        STAGE(As[0], gA, 1, kt2);
        SYNC_PRE(); MFMA_Q(0, 2); SYNC_POST();      // ph5

        READ_AF(1, 4);
        STAGE(Bs[1], gB, 0, kt3);
        SYNC_PRE(); MFMA_Q(4, 0); SYNC_POST();      // ph6

        STAGE(Bs[1], gB, 1, kt3);
        SYNC_PRE(); MFMA_Q(4, 2); SYNC_POST();      // ph7

        BOUNDARY();                                  // K-tile 2t+2 ready
    }

#undef STAGE
#undef READ_AF
#undef READ_BF
#undef MFMA_Q
#undef SYNC_PRE
#undef SYNC_POST
#undef BOUNDARY

    // epilogue
    const int wrow = (w >> 2) * 128;
    const int wcol = (w & 3) * 64;
#pragma unroll
    for (int m = 0; m < 8; ++m) {
        const int rg = row0 + wrow + m * 16 + (l >> 4) * 4;
#pragma unroll
        for (int n = 0; n < 4; ++n) {
            const int cg = col0 + wcol + n * 16 + la;
            f32x4 v = acc[m][n];
            if (EPI == 1) {
                const float bv = bias[cg];
#pragma unroll
                for (int r = 0; r < 4; ++r) v[r] = softplus_f(v[r] + bv);
            }
            if (EPI == 2) {
                ushort* op = (ushort*)(cg < 2048 ? C0 : C1);
                const int cl = cg & 2047;
#pragma unroll
                for (int r = 0; r < 4; ++r)
                    op[(size_t)(rg + r) * Nst + cl] = f2bf(v[r]);
            } else {
#pragma unroll
                for (int r = 0; r < 4; ++r)
                    ((float*)C0)[(size_t)(rg + r) * Nst + cg] = v[r];
            }
        }
    }
}

// Split-K bc GEMM: part[ks] = xc[:, ks*256:(ks+1)*256] @ Wx^T slice.
__global__ __launch_bounds__(256)
void gemm_bc_mfma(const ushort* __restrict__ A, const ushort* __restrict__ Bh,
                  const ushort* __restrict__ Bl, float* __restrict__ part)
{
    __shared__ __attribute__((aligned(16))) ushort As[4096];
    __shared__ __attribute__((aligned(16))) ushort Bhs[1024];
    __shared__ __attribute__((aligned(16))) ushort Bls[1024];

    const int tid  = threadIdx.x;
    const int lane = tid & 63;
    const int wave = tid >> 6;
    const int ks   = blockIdx.x;     // 0..7
    const int mb   = blockIdx.y;     // 0..63
    const int row0 = mb * 128;
    const int kb   = ks * 256;

    const int crow = tid >> 2;
    const int cq   = tid & 3;
    const ushort* Ag0 = A + (size_t)(row0 + crow) * 2048 + kb + cq * 8;
    const ushort* Ag1 = A + (size_t)(row0 + crow + 64) * 2048 + kb + cq * 8;
    const int st0 = lds_addr(crow, cq);
    const int st1 = st0 + 2048;

    const int t2   = tid & 127;
    const int brow = t2 >> 2;        // 0..31
    const int bq   = t2 & 3;
    const ushort* Bg = (tid < 128 ? Bh : Bl) + (size_t)brow * 2048 + kb + bq * 8;
    ushort* Bdst     = (tid < 128 ? Bhs : Bls) + lds_addr(brow, bq);

    const int wm  = wave * 32;
    const int flo = lds_frag_off(lane);
    const int fra = (wm << 5) + flo;
    const int frb = flo;

    f32x4 acc[2][2];
#pragma unroll
    for (int mi = 0; mi < 2; ++mi)
#pragma unroll
        for (int ni = 0; ni < 2; ++ni)
            acc[mi][ni] = (f32x4){0.f, 0.f, 0.f, 0.f};

    uint4 ra0 = *(const uint4*)Ag0, ra1 = *(const uint4*)Ag1;
    uint4 rb  = *(const uint4*)Bg;

    for (int kt = 0; kt < 8; ++kt) {
        __syncthreads();
        *(uint4*)(As + st0) = ra0;
        *(uint4*)(As + st1) = ra1;
        *(uint4*)Bdst = rb;
        __syncthreads();
        if (kt < 7) {
            ra0 = *(const uint4*)(Ag0 + (kt + 1) * 32);
            ra1 = *(const uint4*)(Ag1 + (kt + 1) * 32);
            rb  = *(const uint4*)(Bg + (kt + 1) * 32);
        }
        bf16x8 af[2], bhf[2], blf[2];
#pragma unroll
        for (int mi = 0; mi < 2; ++mi)
            af[mi] = *(const bf16x8*)(As + fra + mi * 512);
#pragma unroll
        for (int ni = 0; ni < 2; ++ni) {
            bhf[ni] = *(const bf16x8*)(Bhs + frb + ni * 512);
            blf[ni] = *(const bf16x8*)(Bls + frb + ni * 512);
        }
#pragma unroll
        for (int mi = 0; mi < 2; ++mi)
#pragma unroll
            for (int ni = 0; ni < 2; ++ni) {
                acc[mi][ni] = __builtin_amdgcn_mfma_f32_16x16x32_bf16(
                    af[mi], bhf[ni], acc[mi][ni], 0, 0, 0);
                acc[mi][ni] = __builtin_amdgcn_mfma_f32_16x16x32_bf16(
                    af[mi], blf[ni], acc[mi][ni], 0, 0, 0);
            }
    }

#pragma unroll
    for (int mi = 0; mi < 2; ++mi) {
        const int rg = row0 + wm + mi * 16 + (lane >> 4) * 4;
#pragma unroll
        for (int ni = 0; ni < 2; ++ni) {
            const int cg = ni * 16 + (lane & 15);
            f32x4 v = acc[mi][ni];
#pragma unroll
            for (int r = 0; r < 4; ++r)
                part[((size_t)ks * 8192 + rg + r) * 32 + cg] = v[r];
        }
    }
}

__global__ __launch_bounds__(256)
void bc_reduce_kernel(const float* __restrict__ part, float* __restrict__ bc)
{
    const int i = blockIdx.x * 256 + threadIdx.x;   // 262144
    float s = 0.f;
#pragma unroll
    for (int ks = 0; ks < 8; ++ks)
        s += part[(size_t)ks * 262144 + i];
    bc[i] = s;
}

// Depthwise causal conv1d (4 taps) + bias + silu; bf16 in, bf16 out.
__global__ __launch_bounds__(256)
void conv_silu_kernel(const ushort* __restrict__ xi, const float* __restrict__ cw,
                      const float* __restrict__ cb, ushort* __restrict__ xc)
{
    const int idx = blockIdx.x * 256 + threadIdx.x;
    const int e   = (idx & 511) << 2;
    const int row = idx >> 9;
    const int l   = row & 2047;

    const float4 w0 = *(const float4*)(cw + (size_t)(e + 0) * 4);
    const float4 w1 = *(const float4*)(cw + (size_t)(e + 1) * 4);
    const float4 w2 = *(const float4*)(cw + (size_t)(e + 2) * 4);
    const float4 w3 = *(const float4*)(cw + (size_t)(e + 3) * 4);

    float4 acc = *(const float4*)(cb + e);

#define CONV_TAP(K_, WSEL)                                                  \
    {                                                                       \
        ushort4 t = *(const ushort4*)(xi + (size_t)(row - (K_)) * 2048 + e);\
        acc.x = fmaf(bf2f(t.x), w0.WSEL, acc.x);                            \
        acc.y = fmaf(bf2f(t.y), w1.WSEL, acc.y);                            \
        acc.z = fmaf(bf2f(t.z), w2.WSEL, acc.z);                            \
        acc.w = fmaf(bf2f(t.w), w3.WSEL, acc.w);                            \
    }
    if (l >= 3) CONV_TAP(3, x)
    if (l >= 2) CONV_TAP(2, y)
    if (l >= 1) CONV_TAP(1, z)
    CONV_TAP(0, w)
#undef CONV_TAP

    ushort4 o;
    o.x = f2bf(silu_f(acc.x)); o.y = f2bf(silu_f(acc.y));
    o.z = f2bf(silu_f(acc.z)); o.w = f2bf(silu_f(acc.w));
    *(ushort4*)(xc + (size_t)row * 2048 + e) = o;
}

// ---- d-parallel chunked selective scan (NCHK chunks of CLEN) ----

__global__ __launch_bounds__(256)
void scan_part1(const ushort* __restrict__ xcb, const float* __restrict__ dbuf,
                const float* __restrict__ bcbuf, const float* __restrict__ A_log,
                float* __restrict__ sum_h, float* __restrict__ sum_p)
{
    __shared__ float bcs[CLEN * 32];           // 8 KB

    const int c    = blockIdx.x >> 5;          // 0..NCHK-2
    const int b    = (blockIdx.x >> 3) & 3;
    const int dblk = blockIdx.x & 7;
    const int d    = dblk * 256 + threadIdx.x;

    const size_t row0 = (size_t)b * 2048 + (size_t)c * CLEN;
    const float* bcp  = bcbuf + row0 * 32;

#pragma unroll
    for (int i = 0; i < (CLEN * 32) / (4 * 256); ++i)
        ((float4*)bcs)[threadIdx.x + i * 256] =
            ((const float4*)bcp)[threadIdx.x + i * 256];

    float Aval[16];
#pragma unroll
    for (int q = 0; q < 4; ++q) {
        float4 al = *(const float4*)(A_log + (size_t)d * 16 + q * 4);
        Aval[q*4+0] = -__expf(al.x); Aval[q*4+1] = -__expf(al.y);
        Aval[q*4+2] = -__expf(al.z); Aval[q*4+3] = -__expf(al.w);
    }

    const float*  dp = dbuf + row0 * 2048 + d;
    const ushort* xp = xcb  + row0 * 2048 + d;

    float h[16];
#pragma unroll
    for (int s = 0; s < 16; ++s) h[s] = 0.f;
    float S = 0.f;

    float wdt[SW], wxv[SW];
#pragma unroll
    for (int j = 0; j < SW; ++j) {
        wdt[j] = dp[(size_t)j * 2048];
        wxv[j] = bf2f(xp[(size_t)j * 2048]);
    }
    __syncthreads();

    for (int l0 = 0; l0 < CLEN; l0 += SW) {
        float ndt[SW], nxv[SW];
        const bool more = (l0 + SW) < CLEN;
        if (more) {
#pragma unroll
            for (int j = 0; j < SW; ++j) {
                const size_t o = (size_t)(l0 + SW + j);
                ndt[j] = dp[o * 2048];
                nxv[j] = bf2f(xp[o * 2048]);
            }
        }
#pragma unroll
        for (int j = 0; j < SW; ++j) {
            const int l = l0 + j;
            const float dt = wdt[j];
            const float t  = dt * wxv[j];
            S += dt;
#pragma unroll
            for (int s = 0; s < 16; ++s)
                h[s] = __expf(dt * Aval[s]) * h[s] + bcs[l * 32 + s] * t;
        }
        if (more) {
#pragma unroll
            for (int j = 0; j < SW; ++j) { wdt[j] = ndt[j]; wxv[j] = nxv[j]; }
        }
    }

    float* sh = sum_h + ((((size_t)c * 4 + b) * 2048 + d) << 4);
    float* sp = sum_p + ((((size_t)c * 4 + b) * 2048 + d) << 4);
#pragma unroll
    for (int q = 0; q < 4; ++q) {
        *(float4*)(sh + q * 4) = make_float4(h[q*4], h[q*4+1], h[q*4+2], h[q*4+3]);
        *(float4*)(sp + q * 4) = make_float4(__expf(Aval[q*4] * S), __expf(Aval[q*4+1] * S),
                                             __expf(Aval[q*4+2] * S), __expf(Aval[q*4+3] * S));
    }
}

__global__ __launch_bounds__(256)
void scan_fold(float* __restrict__ sum_h, const float* __restrict__ sum_p)
{
    const int b = blockIdx.x >> 3;
    const int d = (blockIdx.x & 7) * 256 + threadIdx.x;

    float h[16];
#pragma unroll
    for (int s = 0; s < 16; ++s) h[s] = 0.f;

    for (int c = 0; c < NCHK - 1; ++c) {
        float*       sh = sum_h + ((((size_t)c * 4 + b) * 2048 + d) << 4);
        const float* sp = sum_p + ((((size_t)c * 4 + b) * 2048 + d) << 4);
#pragma unroll
        for (int q = 0; q < 4; ++q) {
            float4 vh = *(const float4*)(sh + q * 4);
            float4 vp = *(const float4*)(sp + q * 4);
            h[q*4+0] = vh.x + vp.x * h[q*4+0];
            h[q*4+1] = vh.y + vp.y * h[q*4+1];
            h[q*4+2] = vh.z + vp.z * h[q*4+2];
            h[q*4+3] = vh.w + vp.w * h[q*4+3];
        }
#pragma unroll
        for (int q = 0; q < 4; ++q)
            *(float4*)(sh + q * 4) = make_float4(h[q*4], h[q*4+1], h[q*4+2], h[q*4+3]);
    }
}

__global__ __launch_bounds__(256)
void scan_part2(const ushort* __restrict__ zbuf, const ushort* __restrict__ xcb,
                const float* __restrict__ dbuf, const float* __restrict__ bcbuf,
                const float* __restrict__ A_log, const float* __restrict__ Dp,
                const float* __restrict__ sum_h, ushort* __restrict__ ybuf)
{
    __shared__ float bcs[CLEN * 32];           // 8 KB

    const int c    = blockIdx.x >> 5;          // 0..NCHK-1
    const int b    = (blockIdx.x >> 3) & 3;
    const int dblk = blockIdx.x & 7;
    const int d    = dblk * 256 + threadIdx.x;

    const size_t row0 = (size_t)b * 2048 + (size_t)c * CLEN;
    const float* bcp  = bcbuf + row0 * 32;

#pragma unroll
    for (int i = 0; i < (CLEN * 32) / (4 * 256); ++i)
        ((float4*)bcs)[threadIdx.x + i * 256] =
            ((const float4*)bcp)[threadIdx.x + i * 256];

    float Aval[16];
#pragma unroll
    for (int q = 0; q < 4; ++q) {
        float4 al = *(const float4*)(A_log + (size_t)d * 16 + q * 4);
        Aval[q*4+0] = -__expf(al.x); Aval[q*4+1] = -__expf(al.y);
        Aval[q*4+2] = -__expf(al.z); Aval[q*4+3] = -__expf(al.w);
    }
    const float Dv = Dp[d];

    float h[16];
    if (c == 0) {
#pragma unroll
        for (int s = 0; s < 16; ++s) h[s] = 0.f;
    } else {
        const float* sh = sum_h + ((((size_t)(c - 1) * 4 + b) * 2048 + d) << 4);
#pragma unroll
        for (int q = 0; q < 4; ++q)
            *(float4*)&h[q*4] = *(const float4*)(sh + q * 4);
    }

    const float*  dp = dbuf + row0 * 2048 + d;
    const ushort* xp = xcb  + row0 * 2048 + d;
    const ushort* zp = zbuf + row0 * 2048 + d;
    ushort*       yp = ybuf + row0 * 2048 + d;

    float wdt[SW], wxv[SW], wzv[SW];
#pragma unroll
    for (int j = 0; j < SW; ++j) {
        wdt[j] = dp[(size_t)j * 2048];
        wxv[j] = bf2f(xp[(size_t)j * 2048]);
        wzv[j] = bf2f(zp[(size_t)j * 2048]);
    }
    __syncthreads();

    for (int l0 = 0; l0 < CLEN; l0 += SW) {
        float ndt[SW], nxv[SW], nzv[SW];
        const bool more = (l0 + SW) < CLEN;
        if (more) {
#pragma unroll
            for (int j = 0; j < SW; ++j) {
                const size_t o = (size_t)(l0 + SW + j);
                ndt[j] = dp[o * 2048];
                nxv[j] = bf2f(xp[o * 2048]);
                nzv[j] = bf2f(zp[o * 2048]);
            }
        }
#pragma unroll
        for (int j = 0; j < SW; ++j) {
            const int l = l0 + j;
            const float dt = wdt[j];
            const float t  = dt * wxv[j];
#pragma unroll
            for (int s = 0; s < 16; ++s)
                h[s] = __expf(dt * Aval[s]) * h[s] + bcs[l * 32 + s] * t;
            float y0 = 0.f, y1 = 0.f, y2 = 0.f, y3 = 0.f;
#pragma unroll
            for (int s = 0; s < 16; s += 4) {
                y0 = fmaf(h[s+0], bcs[l * 32 + 16 + s + 0], y0);
                y1 = fmaf(h[s+1], bcs[l * 32 + 16 + s + 1], y1);
                y2 = fmaf(h[s+2], bcs[l * 32 + 16 + s + 2], y2);
                y3 = fmaf(h[s+3], bcs[l * 32 + 16 + s + 3], y3);
            }
            float y = (y0 + y1) + (y2 + y3) + Dv * wxv[j];
            yp[(size_t)l * 2048] = f2bf(y * silu_f(wzv[j]));
        }
        if (more) {
#pragma unroll
            for (int j = 0; j < SW; ++j) {
                wdt[j] = ndt[j]; wxv[j] = nxv[j]; wzv[j] = nzv[j];
            }
        }
    }
}

extern "C" void kernel_launch(void* const* d_in, const int* in_sizes, int n_in,
                              void* d_out, int out_size, void* d_ws, size_t ws_size,
                              hipStream_t stream)
{
    const float* x          = (const float*)d_in[0];
    const float* in_proj_w  = (const float*)d_in[1];
    const float* conv_w     = (const float*)d_in[2];
    const float* conv_b     = (const float*)d_in[3];
    const float* x_proj_w   = (const float*)d_in[4];
    const float* dt_proj_w  = (const float*)d_in[5];
    const float* dt_proj_b  = (const float*)d_in[6];
    const float* A_log      = (const float*)d_in[7];
    const float* Dp         = (const float*)d_in[8];
    const float* out_proj_w = (const float*)d_in[9];
    float* out = (float*)d_out;

    // Workspace (~232 MB of 256 MiB)
    ushort* XI    = (ushort*)d_ws;                    // 32 MB; later Y'
    ushort* Z     = XI + 16777216;                    // 32 MB
    ushort* XC2   = Z + 16777216;                     // 32 MB
    float*  DELTA = (float*)(XC2 + 16777216);         // 64 MB
    ushort* XP    = (ushort*)DELTA;                   // x' bf16 (pre-DELTA)
    ushort* WINH  = (ushort*)(DELTA + 16777216);      // 8 MB [4096,1024] bf16
    ushort* WDTH  = WINH + 4194304;                   // 8 MB [2048,2048] bf16
    ushort* WOUTH = WDTH + 4194304;                   // 4 MB [1024,2048] bf16
    float*  BC    = (float*)(WOUTH + 2097152);        // 1 MB
    float*  SUMH  = BC + 262144;                      // 16.8 MB (32*4*2048*16)
    float*  SUMP  = SUMH + 4194304;                   // 16.8 MB
    ushort* XPH   = (ushort*)(SUMP + 4194304);        // 128 KB (x_proj hi)
    ushort* XPL   = XPH + 65536;                      // 128 KB
    float*  PART  = (float*)(XPL + 65536);            // 8 MB split-K partials
    ushort* Yp    = XI;

    const dim3 blk(256);
    const dim3 blk8(512);

    // 0) conversions (weights plain bf16 except x_proj hi/lo)
    cvt_bf16_kernel<<<dim3(8192), blk, 0, stream>>>(x, XP);
    cvt_bf16_kernel<<<dim3(4096), blk, 0, stream>>>(in_proj_w, WINH);
    cvt_bf16_kernel<<<dim3(4096), blk, 0, stream>>>(dt_proj_w, WDTH);
    cvt_bf16_kernel<<<dim3(2048), blk, 0, stream>>>(out_proj_w, WOUTH);
    split_w_kernel<<<dim3(64),    blk, 0, stream>>>(x_proj_w, XPH, XPL);

    // 1) xi + z fused (M=8192, N=4096, K=1024 -> 16 K-tiles, 512 blocks)
    gemm256<2, 16><<<dim3(512), blk8, 0, stream>>>(XP, WINH, nullptr, XI, Z, 2048);

    // 2) xc = silu(conv(xi) + b)
    conv_silu_kernel<<<dim3(16384), blk, 0, stream>>>(XI, conv_w, conv_b, XC2);

    // 3) delta = softplus(xc @ Wdt^T + b)  (N=2048, K=2048 -> 256 blocks)
    gemm256<1, 32><<<dim3(256), blk8, 0, stream>>>(XC2, WDTH, dt_proj_b, DELTA, nullptr, 2048);

    // 4) bc = xc @ x_proj_w^T  (split-K MFMA + reduce)
    gemm_bc_mfma<<<dim3(8, 64), blk, 0, stream>>>(XC2, XPH, XPL, PART);
    bc_reduce_kernel<<<dim3(1024), blk, 0, stream>>>(PART, BC);

    // 5) chunked scan: pass1 -> prefix fold -> pass2
    scan_part1<<<dim3((NCHK - 1) * 32), blk, 0, stream>>>(XC2, DELTA, BC, A_log, SUMH, SUMP);
    scan_fold<<<dim3(32), blk, 0, stream>>>(SUMH, SUMP);
    scan_part2<<<dim3(NCHK * 32), blk, 0, stream>>>(Z, XC2, DELTA, BC, A_log, Dp,
                                                    SUMH, Yp);

    // 6) out = y @ Wout^T  (N=1024, K=2048 -> 128 blocks)
    gemm256<0, 32><<<dim3(128), blk8, 0, stream>>>(Yp, WOUTH, nullptr, out, nullptr, 1024);
}